// Round 2
// baseline (166.675 us; speedup 1.0000x reference)
//
#include <hip/hip_runtime.h>

#define BB 4
#define NI 16
#define CC 3
#define HH 256
#define WW 256
#define HWSZ (HH * WW)

// ---------------------------------------------------------------------------
// Per-instance scalars (uniform id -> scalar loads).
// coef = instance_valid * (mode in {0,2,4} ? 1 : mode==3 ? alpha : 0).
// ---------------------------------------------------------------------------
__device__ __forceinline__ float inst_params(
    const float* __restrict__ ml, const float* __restrict__ tp,
    const float* __restrict__ al, const float* __restrict__ iv,
    int id, float th[6]) {
    float best = ml[id * 5];
    int bid = 0;
#pragma unroll
    for (int k = 1; k < 5; ++k) {
        float v = ml[id * 5 + k];
        if (v > best) { best = v; bid = k; }   // strict >: first max, like jnp.argmax
    }
    float coef = (bid == 0 || bid == 2 || bid == 4) ? 1.0f
               : (bid == 3 ? al[id] : 0.0f);
    coef *= iv[id];
#pragma unroll
    for (int k = 0; k < 6; ++k) th[k] = tp[id * 6 + k];
    return coef;
}

// Masked-weight sampler: weights carry validity AND the per-instance coef
// (zero outside / inactive), offsets are clamped in-range so all loads are
// unconditional -> straight-line body, compiler can pipeline across
// instances.
struct Samp {
    int o00, o10, o01, o11;
    float w00, w10, w01, w11;
};

__device__ __forceinline__ Samp make_samp(const float th[6], float coef, int p) {
    const int h = p >> 8, w = p & (WW - 1);
    const float xs = (2 * w + 1) * (1.0f / WW) - 1.0f;
    const float ys = (2 * h + 1) * (1.0f / HH) - 1.0f;
    const float gx = th[0] * xs + th[1] * ys + th[2];
    const float gy = th[3] * xs + th[4] * ys + th[5];
    const float ix = gx * (0.5f * WW) + (0.5f * WW - 0.5f);
    const float iy = gy * (0.5f * HH) + (0.5f * HH - 0.5f);
    const float x0f = floorf(ix), y0f = floorf(iy);
    const float wx1 = ix - x0f, wy1 = iy - y0f;
    const float wx0 = 1.0f - wx1, wy0 = 1.0f - wy1;
    const int x0 = (int)x0f, y0 = (int)y0f;
    const int x1 = x0 + 1, y1 = y0 + 1;
    const float wx0v = ((unsigned)x0 < (unsigned)WW) ? wx0 : 0.0f;
    const float wx1v = ((unsigned)x1 < (unsigned)WW) ? wx1 : 0.0f;
    const float wy0v = ((unsigned)y0 < (unsigned)HH) ? (coef * wy0) : 0.0f;
    const float wy1v = ((unsigned)y1 < (unsigned)HH) ? (coef * wy1) : 0.0f;
    const int x0c = min(max(x0, 0), WW - 1), x1c = min(max(x1, 0), WW - 1);
    const int y0c = min(max(y0, 0), HH - 1), y1c = min(max(y1, 0), HH - 1);
    Samp s;
    s.o00 = y0c * WW + x0c; s.o10 = y0c * WW + x1c;
    s.o01 = y1c * WW + x0c; s.o11 = y1c * WW + x1c;
    s.w00 = wx0v * wy0v; s.w10 = wx1v * wy0v;
    s.w01 = wx0v * wy1v; s.w11 = wx1v * wy1v;
    return s;
}

__device__ __forceinline__ float bilerp(const float* __restrict__ src, const Samp& s) {
    return s.w00 * src[s.o00] + s.w10 * src[s.o10]
         + s.w01 * src[s.o01] + s.w11 * src[s.o11];
}

// ---------------------------------------------------------------------------
// Fused kernel: one thread owns one pixel of one batch across ALL 16
// instances; the instance sum lives in registers, gpi/mpi are written once
// (nontemporal) and never re-read.
//
// The 16-instance loop is FULLY UNROLLED and BRANCHLESS so the scheduler can
// keep gathers from several instances in flight (the previous version's
// per-instance coef branch fenced all load motion -> 24 VGPRs, 30% of HBM
// peak, latency-bound). __launch_bounds__(256,4) caps VGPRs at 128 =
// 16 waves/CU, same occupancy as before but ~5x the loads in flight.
// ---------------------------------------------------------------------------
__global__ __launch_bounds__(256, 4) void fused_k(
    const float* __restrict__ g0,
    const float* __restrict__ m0,
    const float* __restrict__ ml,
    const float* __restrict__ tp,
    const float* __restrict__ al,
    const float* __restrict__ iv,
    const float* __restrict__ i_bg,
    float* __restrict__ out_gpi,
    float* __restrict__ out_mpi,
    float* __restrict__ out_gmid,
    float* __restrict__ out_mmid,
    float* __restrict__ out_ibase) {
    const int b = blockIdx.y;                          // 0..3
    const int p = blockIdx.x * 256 + threadIdx.x;      // pixel in [0, HWSZ)

    float s0 = 0.f, s1 = 0.f, s2 = 0.f, sm = 0.f;

#pragma unroll
    for (int ii = 0; ii < NI; ++ii) {
        const int id = b * NI + ii;
        float th[6];
        const float coef = inst_params(ml, tp, al, iv, id, th);
        const Samp s = make_samp(th, coef, p);

        const float* gsrc = g0 + (size_t)id * CC * HWSZ;
        const float* msrc = m0 + (size_t)id * HWSZ;
        const float v0 = bilerp(gsrc, s);
        const float v1 = bilerp(gsrc + HWSZ, s);
        const float v2 = bilerp(gsrc + 2 * HWSZ, s);
        const float vm = bilerp(msrc, s);

        float* gp = out_gpi + (size_t)id * CC * HWSZ + p;
        __builtin_nontemporal_store(v0, gp);
        __builtin_nontemporal_store(v1, gp + HWSZ);
        __builtin_nontemporal_store(v2, gp + 2 * HWSZ);
        __builtin_nontemporal_store(vm, out_mpi + (size_t)id * HWSZ + p);

        s0 += v0; s1 += v1; s2 += v2; sm += vm;
    }

    const size_t ob = (size_t)b * CC * HWSZ + p;
    out_gmid[ob]             = s0;
    out_gmid[ob + HWSZ]      = s1;
    out_gmid[ob + 2 * HWSZ]  = s2;
    out_ibase[ob]            = s0 + i_bg[ob];
    out_ibase[ob + HWSZ]     = s1 + i_bg[ob + HWSZ];
    out_ibase[ob + 2 * HWSZ] = s2 + i_bg[ob + 2 * HWSZ];
    out_mmid[(size_t)b * HWSZ + p] = fminf(fmaxf(sm, 0.f), 1.f);
}

extern "C" void kernel_launch(void* const* d_in, const int* in_sizes, int n_in,
                              void* d_out, int out_size, void* d_ws, size_t ws_size,
                              hipStream_t stream) {
    const float* g0          = (const float*)d_in[0];
    const float* m0          = (const float*)d_in[1];
    const float* mode_logits = (const float*)d_in[2];
    const float* tp          = (const float*)d_in[3];
    const float* alpha       = (const float*)d_in[4];
    const float* iv          = (const float*)d_in[5];
    const float* i_bg        = (const float*)d_in[6];

    float* out       = (float*)d_out;
    float* out_gpi   = out;                                        // [B,NI,C,H,W]
    float* out_mpi   = out_gpi  + (size_t)BB * NI * CC * HWSZ;     // [B,NI,1,H,W]
    float* out_gmid  = out_mpi  + (size_t)BB * NI * HWSZ;          // [B,C,H,W]
    float* out_mmid  = out_gmid + (size_t)BB * CC * HWSZ;          // [B,1,H,W]
    float* out_ibase = out_mmid + (size_t)BB * HWSZ;               // [B,C,H,W]

    dim3 grid(HWSZ / 256, BB);                                     // 256 x 4
    fused_k<<<grid, 256, 0, stream>>>(g0, m0, mode_logits, tp, alpha, iv, i_bg,
                                      out_gpi, out_mpi,
                                      out_gmid, out_mmid, out_ibase);
}

// Round 3
// 150.472 us; speedup vs baseline: 1.1077x; 1.1077x over previous
//
#include <hip/hip_runtime.h>

#define BB 4
#define NI 16
#define CC 3
#define HH 256
#define WW 256
#define HWSZ (HH * WW)

// float2 with 4-byte alignment promise: bilinear tap pairs are only
// dword-aligned. Backend emits unaligned-capable dwordx2 (or splits legally).
typedef float f2v __attribute__((ext_vector_type(2)));
typedef f2v f2u __attribute__((aligned(4)));

__device__ __forceinline__ f2v ld2(const float* __restrict__ p) {
    return *reinterpret_cast<const f2u*>(p);
}

// ---------------------------------------------------------------------------
// Per-instance scalars (uniform id -> scalar loads).
// coef = instance_valid * (mode in {0,2,4} ? 1 : mode==3 ? alpha : 0).
// ---------------------------------------------------------------------------
__device__ __forceinline__ float inst_params(
    const float* __restrict__ ml, const float* __restrict__ tp,
    const float* __restrict__ al, const float* __restrict__ iv,
    int id, float th[6]) {
    float best = ml[id * 5];
    int bid = 0;
#pragma unroll
    for (int k = 1; k < 5; ++k) {
        float v = ml[id * 5 + k];
        if (v > best) { best = v; bid = k; }   // strict >: first max, like jnp.argmax
    }
    float coef = (bid == 0 || bid == 2 || bid == 4) ? 1.0f
               : (bid == 3 ? al[id] : 0.0f);
    coef *= iv[id];
#pragma unroll
    for (int k = 0; k < 6; ++k) th[k] = tp[id * 6 + k];
    return coef;
}

// ---------------------------------------------------------------------------
// Pair-based sampler: since x1 = x0+1 and y1 = y0+1, each (row, plane) tap
// pair is one float2 gather based at bx = clamp(x0, 0, W-2). When clamping
// shifts the base (x0 OOB low/high) the x-weights swap columns; OOB weights
// are already zeroed, so the algebra stays exact. Same for the row pair.
// 8 VMEM gathers per instance instead of 16 -> halves TA address-divergence
// cost (the bottleneck: slanted warp rows make each gather touch ~8+ lines).
// ---------------------------------------------------------------------------
struct Samp {
    int oA, oB;            // row-pair base offsets (column bx)
    float wxA, wxB;        // x weights for columns bx, bx+1
    float wyA, wyB;        // y weights for rows by, by+1 (coef folded in)
};

__device__ __forceinline__ Samp make_samp(const float th[6], float coef, int p) {
    const int h = p >> 8, w = p & (WW - 1);
    const float xs = (2 * w + 1) * (1.0f / WW) - 1.0f;
    const float ys = (2 * h + 1) * (1.0f / HH) - 1.0f;
    const float gx = th[0] * xs + th[1] * ys + th[2];
    const float gy = th[3] * xs + th[4] * ys + th[5];
    const float ix = gx * (0.5f * WW) + (0.5f * WW - 0.5f);
    const float iy = gy * (0.5f * HH) + (0.5f * HH - 0.5f);
    const float x0f = floorf(ix), y0f = floorf(iy);
    const float wx1 = ix - x0f, wy1 = iy - y0f;
    const float wx0 = 1.0f - wx1, wy0 = 1.0f - wy1;
    const int x0 = (int)x0f, y0 = (int)y0f;
    const int x1 = x0 + 1, y1 = y0 + 1;
    // validity-masked weights (zero outside the source image)
    const float wx0v = ((unsigned)x0 < (unsigned)WW) ? wx0 : 0.0f;
    const float wx1v = ((unsigned)x1 < (unsigned)WW) ? wx1 : 0.0f;
    const float wy0v = ((unsigned)y0 < (unsigned)HH) ? (coef * wy0) : 0.0f;
    const float wy1v = ((unsigned)y1 < (unsigned)HH) ? (coef * wy1) : 0.0f;
    // pair bases; weight-swap when the clamp shifted the base
    const int bx = min(max(x0, 0), WW - 2);
    const int by = min(max(y0, 0), HH - 2);
    const bool sx = (x0 != bx);
    const bool sy = (y0 != by);
    Samp s;
    s.wxA = sx ? wx1v : wx0v;  s.wxB = sx ? wx0v : wx1v;
    s.wyA = sy ? wy1v : wy0v;  s.wyB = sy ? wy0v : wy1v;
    s.oA = by * WW + bx;
    s.oB = s.oA + WW;
    return s;
}

__device__ __forceinline__ float bilerp(const float* __restrict__ src, const Samp& s) {
    const f2v a = ld2(src + s.oA);
    const f2v b = ld2(src + s.oB);
    return s.wyA * (s.wxA * a.x + s.wxB * a.y)
         + s.wyB * (s.wxA * b.x + s.wxB * b.y);
}

// ---------------------------------------------------------------------------
// Fused kernel (round-1 structure, proven fastest): one thread owns one pixel
// across all 16 instances; instance sum in registers; gpi/mpi written once
// (nontemporal), never re-read. Rolled loop + coef-skip branch keep all
// blocks in instance-lockstep (L2-friendly: FETCH ~50 MB, vs 126 MB when
// unrolled branchless) and skip inactive instances entirely.
// ---------------------------------------------------------------------------
__global__ __launch_bounds__(512) void fused_k(
    const float* __restrict__ g0,
    const float* __restrict__ m0,
    const float* __restrict__ ml,
    const float* __restrict__ tp,
    const float* __restrict__ al,
    const float* __restrict__ iv,
    const float* __restrict__ i_bg,
    float* __restrict__ out_gpi,
    float* __restrict__ out_mpi,
    float* __restrict__ out_gmid,
    float* __restrict__ out_mmid,
    float* __restrict__ out_ibase) {
    const int b = blockIdx.y;                          // 0..3
    const int p = blockIdx.x * 512 + threadIdx.x;      // pixel in [0, HWSZ)

    float s0 = 0.f, s1 = 0.f, s2 = 0.f, sm = 0.f;

#pragma unroll 2
    for (int ii = 0; ii < NI; ++ii) {
        const int id = b * NI + ii;
        float th[6];
        const float coef = inst_params(ml, tp, al, iv, id, th);

        float v0 = 0.f, v1 = 0.f, v2 = 0.f, vm = 0.f;
        if (coef != 0.0f) {                            // block-uniform branch
            const Samp s = make_samp(th, coef, p);
            const float* gsrc = g0 + (size_t)id * CC * HWSZ;
            const float* msrc = m0 + (size_t)id * HWSZ;
            v0 = bilerp(gsrc, s);
            v1 = bilerp(gsrc + HWSZ, s);
            v2 = bilerp(gsrc + 2 * HWSZ, s);
            vm = bilerp(msrc, s);
        }

        float* gp = out_gpi + (size_t)id * CC * HWSZ + p;
        __builtin_nontemporal_store(v0, gp);
        __builtin_nontemporal_store(v1, gp + HWSZ);
        __builtin_nontemporal_store(v2, gp + 2 * HWSZ);
        __builtin_nontemporal_store(vm, out_mpi + (size_t)id * HWSZ + p);

        s0 += v0; s1 += v1; s2 += v2; sm += vm;
    }

    const size_t ob = (size_t)b * CC * HWSZ + p;
    out_gmid[ob]             = s0;
    out_gmid[ob + HWSZ]      = s1;
    out_gmid[ob + 2 * HWSZ]  = s2;
    out_ibase[ob]            = s0 + i_bg[ob];
    out_ibase[ob + HWSZ]     = s1 + i_bg[ob + HWSZ];
    out_ibase[ob + 2 * HWSZ] = s2 + i_bg[ob + 2 * HWSZ];
    out_mmid[(size_t)b * HWSZ + p] = fminf(fmaxf(sm, 0.f), 1.f);
}

extern "C" void kernel_launch(void* const* d_in, const int* in_sizes, int n_in,
                              void* d_out, int out_size, void* d_ws, size_t ws_size,
                              hipStream_t stream) {
    const float* g0          = (const float*)d_in[0];
    const float* m0          = (const float*)d_in[1];
    const float* mode_logits = (const float*)d_in[2];
    const float* tp          = (const float*)d_in[3];
    const float* alpha       = (const float*)d_in[4];
    const float* iv          = (const float*)d_in[5];
    const float* i_bg        = (const float*)d_in[6];

    float* out       = (float*)d_out;
    float* out_gpi   = out;                                        // [B,NI,C,H,W]
    float* out_mpi   = out_gpi  + (size_t)BB * NI * CC * HWSZ;     // [B,NI,1,H,W]
    float* out_gmid  = out_mpi  + (size_t)BB * NI * HWSZ;          // [B,C,H,W]
    float* out_mmid  = out_gmid + (size_t)BB * CC * HWSZ;          // [B,1,H,W]
    float* out_ibase = out_mmid + (size_t)BB * HWSZ;               // [B,C,H,W]

    dim3 grid(HWSZ / 512, BB);                                     // 128 x 4
    fused_k<<<grid, 512, 0, stream>>>(g0, m0, mode_logits, tp, alpha, iv, i_bg,
                                      out_gpi, out_mpi,
                                      out_gmid, out_mmid, out_ibase);
}